// Round 2
// baseline (212.723 us; speedup 1.0000x reference)
//
#include <hip/hip_runtime.h>
#include <math.h>

typedef short s16x8 __attribute__((ext_vector_type(8)));
typedef short s16x4 __attribute__((ext_vector_type(4)));
typedef float f32x4 __attribute__((ext_vector_type(4)));

#define N_NODES 100000
#define N_EDGESC 1000000
#define NODE_DIM 64
#define HID 128

// round-to-nearest-even f32 -> bf16 bits
__device__ __forceinline__ unsigned short f2bf(float f){
  unsigned u = __float_as_uint(f);
  u += 0x7fffu + ((u >> 16) & 1u);
  return (unsigned short)(u >> 16);
}

// Fused prep: blocks [0,2048) cast node table f32->bf16; blocks [2048,2176)
// pack W1^T and W2^T into MFMA *fragment order*:
//   wf[(layer*32 + f)*512 + l*8 + j] = W[k][n],  f = t*8+nt, l = q*16+s,
//   k = t*32 + q*8 + j, n = nt*16 + s
// so that LDS staging and per-(t,nt) fragment reads are lane-linear
// (conflict-free, no swizzle needed).
__global__ void prep_kernel(const float* __restrict__ node,
                            const float* __restrict__ w1,
                            const float* __restrict__ w2,
                            unsigned short* __restrict__ nodeb,
                            unsigned short* __restrict__ wf){
  const int b = blockIdx.x;
  if (b < 2048){
    int i = b * 256 + threadIdx.x;
    const int n4 = N_NODES * NODE_DIM / 4;
    const int stride = 2048 * 256;
    for (; i < n4; i += stride){
      const float4 v = reinterpret_cast<const float4*>(node)[i];
      ushort4 o;
      o.x = f2bf(v.x); o.y = f2bf(v.y); o.z = f2bf(v.z); o.w = f2bf(v.w);
      reinterpret_cast<ushort4*>(nodeb)[i] = o;
    }
  } else {
    const int i = (b - 2048) * 256 + threadIdx.x;   // 0..32767
    const float* w = (i < 16384) ? w1 : w2;
    const int ii = i & 16383;
    const int f = ii >> 9, rem = ii & 511, l = rem >> 3, j = rem & 7;
    const int t = f >> 3, nt = f & 7, q = l >> 4, s = l & 15;
    const int k = t * 32 + q * 8 + j, n = nt * 16 + s;
    wf[i] = f2bf(w[k * 128 + n]);
  }
}

// Fused 3-layer edge MLP.  Per wave: 32 edges (2 e-tiles of 16).
// mfma_f32_16x16x32_bf16:  A = W^T fragment (row n = nt*16+s, k = t*32+q*8+j),
// B = feat/h (k same, col edge = s).  D: lane holds h[n = nt*16+q*4+r][edge s].
// W fragments live in a single 32KB LDS buffer in fragment order (lane-linear
// reads).  Layer1->layer2 crossover (D-layout -> B-layout) runs in each wave's
// private 8KB slice of the same buffer after W1 is dead.  W2 re-staged after.
__global__ __launch_bounds__(256, 4) void mlp_main(
    const int* __restrict__ eidx,              // [2][E] int32
    const unsigned short* __restrict__ nodeb,  // [N][64] bf16 bits
    const unsigned short* __restrict__ wf,     // [2][32][512] bf16 fragment-order
    const float* __restrict__ b1, const float* __restrict__ b2,
    const float* __restrict__ w3, const float* __restrict__ b3,
    float* __restrict__ out)
{
  __shared__ unsigned short wlds[16384];   // 32 KB

  const int tid  = threadIdx.x;
  const int wave = tid >> 6;
  const int lane = tid & 63;
  const int q    = lane >> 4;
  const int s    = lane & 15;

  const long ebase = (long)blockIdx.x * 128 + wave * 32;

  // ---- gather feat B-fragments straight from global (bf16 node table, L3-hot)
  s16x8 bf1[2][4];
  #pragma unroll
  for (int et = 0; et < 2; ++et){
    long e = ebase + et * 16 + s;
    if (e > (long)N_EDGESC - 1) e = N_EDGESC - 1;
    const int is = eidx[e];
    const int id = eidx[N_EDGESC + e];
    #pragma unroll
    for (int t = 0; t < 4; ++t){
      const int node = (t < 2) ? is : id;
      const int c = (t & 1) * 32 + q * 8;
      bf1[et][t] = *reinterpret_cast<const s16x8*>(nodeb + node * NODE_DIM + c);
    }
  }

  // ---- stage W1 fragments (straight 32KB copy, lane-linear, conflict-free)
  #pragma unroll
  for (int j = 0; j < 8; ++j){
    const int c = j * 256 + tid;
    reinterpret_cast<int4*>(wlds)[c] = reinterpret_cast<const int4*>(wf)[c];
  }
  __syncthreads();

  f32x4 acc[2][8];
  #pragma unroll
  for (int et = 0; et < 2; ++et)
    #pragma unroll
    for (int nt = 0; nt < 8; ++nt)
      acc[et][nt] = (f32x4){0.f, 0.f, 0.f, 0.f};

  // ---- layer 1: fragment reads are lane-linear (f*1024 + lane*16 bytes)
  #pragma unroll
  for (int t = 0; t < 4; ++t){
    #pragma unroll
    for (int nt = 0; nt < 8; ++nt){
      const s16x8 a = *reinterpret_cast<const s16x8*>(wlds + (t * 8 + nt) * 512 + lane * 8);
      acc[0][nt] = __builtin_amdgcn_mfma_f32_16x16x32_bf16(a, bf1[0][t], acc[0][nt], 0, 0, 0);
      acc[1][nt] = __builtin_amdgcn_mfma_f32_16x16x32_bf16(a, bf1[1][t], acc[1][nt], 0, 0, 0);
    }
  }
  __syncthreads();   // all waves done reading W1

  // ---- bias+relu+bf16 crossover in this wave's private 8KB slice of wlds.
  // write: lane-linear 8B; read: two 8B at +0/+128 (ds_read2_b64 pattern).
  char* hb = (char*)wlds + wave * 8192;
  s16x8 bf2[2][4];
  #pragma unroll
  for (int et = 0; et < 2; ++et){
    #pragma unroll
    for (int nt = 0; nt < 8; ++nt){
      const float4 bb = *reinterpret_cast<const float4*>(b1 + nt * 16 + q * 4);
      ushort4 pk;
      pk.x = f2bf(fmaxf(acc[et][nt][0] + bb.x, 0.f));
      pk.y = f2bf(fmaxf(acc[et][nt][1] + bb.y, 0.f));
      pk.z = f2bf(fmaxf(acc[et][nt][2] + bb.z, 0.f));
      pk.w = f2bf(fmaxf(acc[et][nt][3] + bb.w, 0.f));
      *reinterpret_cast<ushort4*>(hb + nt * 512 + lane * 8) = pk;
    }
    #pragma unroll
    for (int t = 0; t < 4; ++t){
      const int nt2 = 2 * t + (q >> 1);
      const char* base = hb + nt2 * 512 + ((2 * q) & 3) * 128 + s * 8;
      const s16x4 lo = *reinterpret_cast<const s16x4*>(base);
      const s16x4 hi = *reinterpret_cast<const s16x4*>(base + 128);
      s16x8 r;
      r[0] = lo[0]; r[1] = lo[1]; r[2] = lo[2]; r[3] = lo[3];
      r[4] = hi[0]; r[5] = hi[1]; r[6] = hi[2]; r[7] = hi[3];
      bf2[et][t] = r;
    }
  }
  __syncthreads();   // all waves done with crossover slices

  // ---- stage W2 fragments (overwrite same 32KB)
  #pragma unroll
  for (int j = 0; j < 8; ++j){
    const int c = j * 256 + tid;
    reinterpret_cast<int4*>(wlds)[c] = reinterpret_cast<const int4*>(wf + 16384)[c];
  }
  __syncthreads();

  #pragma unroll
  for (int et = 0; et < 2; ++et)
    #pragma unroll
    for (int nt = 0; nt < 8; ++nt)
      acc[et][nt] = (f32x4){0.f, 0.f, 0.f, 0.f};

  // ---- layer 2
  #pragma unroll
  for (int t = 0; t < 4; ++t){
    #pragma unroll
    for (int nt = 0; nt < 8; ++nt){
      const s16x8 a = *reinterpret_cast<const s16x8*>(wlds + (t * 8 + nt) * 512 + lane * 8);
      acc[0][nt] = __builtin_amdgcn_mfma_f32_16x16x32_bf16(a, bf2[0][t], acc[0][nt], 0, 0, 0);
      acc[1][nt] = __builtin_amdgcn_mfma_f32_16x16x32_bf16(a, bf2[1][t], acc[1][nt], 0, 0, 0);
    }
  }

  // ---- layer 3: bias+relu, dot with W3, quadrant reduce, sigmoid
  const float bias3 = b3[0];
  #pragma unroll
  for (int et = 0; et < 2; ++et){
    float p = 0.f;
    #pragma unroll
    for (int nt = 0; nt < 8; ++nt){
      const float4 bb = *reinterpret_cast<const float4*>(b2 + nt * 16 + q * 4);
      const float4 ww = *reinterpret_cast<const float4*>(w3 + nt * 16 + q * 4);
      p += fmaxf(acc[et][nt][0] + bb.x, 0.f) * ww.x;
      p += fmaxf(acc[et][nt][1] + bb.y, 0.f) * ww.y;
      p += fmaxf(acc[et][nt][2] + bb.z, 0.f) * ww.z;
      p += fmaxf(acc[et][nt][3] + bb.w, 0.f) * ww.w;
    }
    p += __shfl_xor(p, 16);
    p += __shfl_xor(p, 32);
    const long e = ebase + et * 16 + s;
    if (q == 0 && e < N_EDGESC){
      out[e] = 1.f / (1.f + expf(-(p + bias3)));
    }
  }
}

extern "C" void kernel_launch(void* const* d_in, const int* in_sizes, int n_in,
                              void* d_out, int out_size, void* d_ws, size_t ws_size,
                              hipStream_t stream){
  const float* node_rep = (const float*)d_in[0];
  const int*   eidx     = (const int*)d_in[1];
  const float* W1 = (const float*)d_in[2];
  const float* b1 = (const float*)d_in[3];
  const float* W2 = (const float*)d_in[4];
  const float* b2 = (const float*)d_in[5];
  const float* W3 = (const float*)d_in[6];
  const float* b3 = (const float*)d_in[7];
  float* out = (float*)d_out;

  unsigned short* nodeb = (unsigned short*)d_ws;
  unsigned short* wf = (unsigned short*)((char*)d_ws + (size_t)N_NODES * NODE_DIM * 2);

  prep_kernel<<<2048 + 128, 256, 0, stream>>>(node_rep, W1, W2, nodeb, wf);

  const int nblocks = (N_EDGESC + 127) / 128;
  mlp_main<<<nblocks, 256, 0, stream>>>(eidx, nodeb, wf, b1, b2, W3, b3, out);
}